// Round 11
// baseline (310.052 us; speedup 1.0000x reference)
//
#include <hip/hip_runtime.h>
#include <hip/hip_bf16.h>
#include <stdint.h>

// Problem constants
#define B_ROWS 32768
#define NUM_IN 1024
#define HID    2048
#define NPAD   64     // 37 logits padded to 64

typedef __attribute__((ext_vector_type(8))) short bf16x8;
typedef __attribute__((ext_vector_type(4))) float f32x4;
typedef unsigned short ushort_t;

__device__ __forceinline__ unsigned short f2bf(float f){
  union { float f; uint32_t u; } x; x.f = f;
  uint32_t u = x.u;
  return (unsigned short)((u + 0x7FFFu + ((u >> 16) & 1u)) >> 16);
}

// ---------------- discretizer scan (per batch element) ----------------
__device__ __forceinline__ int disc_step(
    float cam0, float cam1, const int a[5],
    float& ac0, float& ac1, float& delta,
    int r[5], bool& dch, int& cam_steps, bool& committed, float& norm)
{
  const int RS[5] = {6, 8, 10, 11, 14};
  norm += committed ? 0.0f : 1.0f;
  bool commit = ((fabsf(cam0) < 1e-5f) && (fabsf(cam1) < 1e-5f)) || (cam_steps >= 6);
  #pragma unroll
  for (int i = 0; i < 5; ++i) commit = commit && (r[i] == a[i]);
  int dac = 0;
  bool modified = commit;
  #pragma unroll
  for (int i = 0; i < 5; ++i){
    bool disc = (!modified) && (r[i] != a[i]);
    if (disc){
      dac = (a[i] == 0) ? (r[i] - 1 + RS[i]) : (a[i] - 1 + RS[i]);
      r[i] = a[i];
      modified = true;
    }
  }
  float d2 = delta * 2.0f;
  // NOTE: reference compares BOTH cam0 and cam1 against ac[:,0] — replicate.
  bool dmask = (!modified) && (!dch) &&
               ((fabsf(cam0 - ac0) > d2) || (fabsf(cam1 - ac0) > d2));
  if (dmask){ dac = 5; delta = fminf(d2, 0.5f); modified = true; }
  if (!modified){
    float sx = (cam0 < ac0) ? -1.0f : 1.0f;
    float sy = (cam1 < ac1) ? -1.0f : 1.0f;
    dac = (sx < 0.0f) ? ((sy < 0.0f) ? 1 : 3) : ((sy < 0.0f) ? 2 : 4);
    ac0 += sx * delta; ac1 += sy * delta;
    delta *= 0.5f;
    dch = true;
    cam_steps += 1;
  }
  committed = committed || commit;
  return dac;
}

// ---------------- prep: W1 fragment-pack | W2^T | discretizer (no fc pass) ----------------
// block ranges: [0,544) w1 pack (17x32 tiles of 64x64); [544,1056) w2t ; [1056,1184) disc
__global__ void k_prep(const float* __restrict__ W1, const float* __restrict__ W2,
                       const float* __restrict__ camera, const float* __restrict__ rand_u,
                       const int* __restrict__ afb, const int* __restrict__ alr,
                       const int* __restrict__ ajp, const int* __restrict__ ass,
                       const int* __restrict__ aat,
                       unsigned short* __restrict__ xtail, unsigned short* __restrict__ w1p,
                       unsigned short* __restrict__ w2t, int* __restrict__ tgt)
{
  __shared__ float lt[64][65];      // transpose tile (+1 pad, conflict-free)
  const int b = blockIdx.x;
  const int tid = threadIdx.x;
  if (b < 544){
    // W1 [1064][2048] -> fragment-major pack w1p[cgrp][kt][wn][q=nh*4+ni*2+kk][lane][8]
    const int kt = b % 17, nt = b / 17;
    const int k0 = kt * 64, n0 = nt * 64;
    const int cgrp = nt >> 2, wn = nt & 3;
    const int c = tid & 63, rq = tid >> 6;
    #pragma unroll
    for (int rr = 0; rr < 16; ++rr){
      const int r = rr * 4 + rq;
      const int k = k0 + r;
      lt[r][c] = (k < 1064) ? W1[(size_t)k * HID + n0 + c] : 0.0f;
    }
    __syncthreads();
    #pragma unroll
    for (int s = 0; s < 2; ++s){
      const int idx = s * 256 + tid;
      const int ln = idx & 63, q = idx >> 6;         // q = nh*4+ni*2+kk
      const int lr2 = ln & 15, lg2 = ln >> 4;
      const int np = (q >> 2) * 32 + ((q >> 1) & 1) * 16 + lr2;  // n-local
      const int kx = (q & 1) * 32 + lg2 * 8;                     // k-local
      uint4 pk;
      uint32_t w[4];
      #pragma unroll
      for (int e = 0; e < 4; ++e){
        unsigned short lo = f2bf(lt[kx + 2*e][np]);
        unsigned short hi = f2bf(lt[kx + 2*e + 1][np]);
        w[e] = (uint32_t)lo | ((uint32_t)hi << 16);
      }
      pk.x = w[0]; pk.y = w[1]; pk.z = w[2]; pk.w = w[3];
      *(uint4*)(w1p + (((size_t)cgrp*17 + kt) << 14) + (wn << 12) + q*512 + ln*8) = pk;
    }
    return;
  }
  if (b < 1056){
    int idx = (b - 544) * 256 + tid;                 // over 64*2048
    int n = idx >> 11;
    int k = idx & (HID - 1);
    float v = (n < 37) ? W2[(size_t)k * 37 + n] : 0.0f;
    w2t[idx] = f2bf(v);
    return;
  }
  // discretizer
  int row = (b - 1056) * 256 + tid;
  float cam0 = camera[2*row], cam1 = camera[2*row + 1];
  int a[5] = { afb[row], alr[row], ajp[row], ass[row], aat[row] };

  float ac0 = 0.f, ac1 = 0.f, delta = 0.0625f, norm = 0.f;
  int r[5] = {0,0,0,0,0};
  bool dch = false, committed = false; int cam_steps = 0;
  for (int t = 0; t < 20; ++t)
    disc_step(cam0, cam1, a, ac0, ac1, delta, r, dch, cam_steps, committed, norm);

  int rs = (int)(rand_u[row] * norm);
  if (rs > 19) rs = 19;
  if (rs < 0) rs = 0;

  ac0 = 0.f; ac1 = 0.f; delta = 0.0625f; norm = 0.f;
  r[0]=r[1]=r[2]=r[3]=r[4]=0; dch = false; committed = false; cam_steps = 0;
  for (int t = 0; t < rs; ++t)
    disc_step(cam0, cam1, a, ac0, ac1, delta, r, dch, cam_steps, committed, norm);

  float vec[40];
  #pragma unroll
  for (int j = 0; j < 40; ++j) vec[j] = 0.0f;
  vec[0] = ac0; vec[1] = ac1;
  const int offs[5] = {2, 5, 8, 10, 14};
  #pragma unroll
  for (int i = 0; i < 5; ++i) vec[offs[i] + r[i]] = 1.0f;
  vec[38] = delta; vec[39] = dch ? 1.0f : 0.0f;

  int dac = disc_step(cam0, cam1, a, ac0, ac1, delta, r, dch, cam_steps, committed, norm);
  tgt[row] = dac;

  unsigned short* o = xtail + (size_t)row * 64;
  #pragma unroll
  for (int j = 0; j < 40; ++j) o[j] = f2bf(vec[j]);
  #pragma unroll
  for (int j = 40; j < 64; ++j) o[j] = 0;
}

// ---------------- GEMM1: 256x256, A reg-staged (fc f32 -> bf16 in-flight), B from L2 ----------------
// LDS: A triple buffer at byte 0 / 32768 / 65536 (256 rows x 128 B). Epilogue reuses full 128 KB.

// A fragment batch (8 x ds_read_b128); BO = byte offset of buffer (compile-time)
#define LDA_T(BO, MH) do { \
    _Pragma("unroll") for (int mi_ = 0; mi_ < 4; ++mi_) \
    _Pragma("unroll") for (int kk_ = 0; kk_ < 2; ++kk_) \
      aR[mi_][kk_] = *(const bf16x8*)(aBk[kk_] + (BO) + (((MH)*64 + mi_*16)*128)); \
  } while(0)

// B half-tile load: 4 x global_load_dwordx4 (1KB each, coalesced) from fragment-packed w1p
#define GLBH(BANK, KT, NH) do { \
    const ushort_t* bp_ = w1p + (((size_t)cgrp*17 + (KT)) << 14) + (wn << 12) + ((NH)*4)*512 + lane*8; \
    _Pragma("unroll") for (int ni_ = 0; ni_ < 2; ++ni_) \
    _Pragma("unroll") for (int kk_ = 0; kk_ < 2; ++kk_) \
      BANK[ni_][kk_] = *(const bf16x8*)(bp_ + (ni_*2 + kk_)*512); \
  } while(0)

// one quadrant: 16 MFMA
#define MMA(MH, NH, BH) do { \
    __builtin_amdgcn_s_setprio(1); \
    _Pragma("unroll") for (int mi_ = 0; mi_ < 4; ++mi_) \
    _Pragma("unroll") for (int ni_ = 0; ni_ < 2; ++ni_) \
    _Pragma("unroll") for (int kk_ = 0; kk_ < 2; ++kk_) \
      acc[(MH)*4+mi_][(NH)*2+ni_] = __builtin_amdgcn_mfma_f32_16x16x32_bf16( \
          aR[mi_][kk_], BH[ni_][kk_], acc[(MH)*4+mi_][(NH)*2+ni_], 0, 0, 0); \
    __builtin_amdgcn_s_setprio(0); \
  } while(0)

// A staging: thread (s_r = t>>1, s_h = t&1) covers fc[brow+s_r][KT*64 + s_h*32 .. +31].
// Batch H = f32 elems H*16..H*16+15 of the thread's 32.
#define LOADH(DST, KT, H) do { \
    const float4* fp_ = (const float4*)(fc + (size_t)(brow + s_r) * NUM_IN + ((KT) << 6) + s_h*32 + (H)*16); \
    _Pragma("unroll") for (int j_ = 0; j_ < 4; ++j_) DST[j_] = fp_[j_]; \
  } while(0)

// Write batch H -> chunks (s_h*4 + H*2 + cc), swizzled by row&7 (matches read XOR).
#define WRITEH(SRC, SBO, H) do { \
    _Pragma("unroll") for (int cc_ = 0; cc_ < 2; ++cc_){ \
      float4 u_ = SRC[2*cc_], v_ = SRC[2*cc_ + 1]; \
      uint4 pk_; \
      pk_.x = (uint32_t)f2bf(u_.x) | ((uint32_t)f2bf(u_.y) << 16); \
      pk_.y = (uint32_t)f2bf(u_.z) | ((uint32_t)f2bf(u_.w) << 16); \
      pk_.z = (uint32_t)f2bf(v_.x) | ((uint32_t)f2bf(v_.y) << 16); \
      pk_.w = (uint32_t)f2bf(v_.z) | ((uint32_t)f2bf(v_.w) << 16); \
      const int ch_ = s_h*4 + (H)*2 + cc_; \
      *(uint4*)(lds + (SBO) + s_r*64 + ((ch_ ^ (s_r & 7)) << 3)) = pk_; \
    } \
  } while(0)

// Tail tile (16): bf16 from xtail, 4 swizzled 16B writes
#define STAGE_TAIL(SBO) do { \
    const uint4* tp_ = (const uint4*)(xtail + (size_t)(brow + s_r) * 64 + s_h*32); \
    _Pragma("unroll") for (int c_ = 0; c_ < 4; ++c_){ \
      uint4 pk_ = tp_[c_]; \
      const int ch_ = s_h*4 + c_; \
      *(uint4*)(lds + (SBO) + s_r*64 + ((ch_ ^ (s_r & 7)) << 3)) = pk_; \
    } \
  } while(0)

#define BAR() __builtin_amdgcn_s_barrier()
#define LGKM0() asm volatile("s_waitcnt lgkmcnt(0)" ::: "memory")

__global__ __launch_bounds__(512, 2) void k_gemm1(const float* __restrict__ fc,
                                                  const ushort_t* __restrict__ xtail,
                                                  const ushort_t* __restrict__ w1p,
                                                  const ushort_t* __restrict__ w2t,
                                                  const float* __restrict__ b1,
                                                  float* __restrict__ pbuf)
{
  __shared__ ushort_t lds[65536];   // 128 KiB (96 KB A triple-buffer in loop; full in epilogue)
  const int t = threadIdx.x;        // 0..511
  const int lane = t & 63;
  const int wid = t >> 6, wm = wid >> 2, wn = wid & 3;
  const int lr = lane & 15, lg = lane >> 4;

  // XCD-aware swizzle (nwg=1024 divisible by 8 -> bijective).
  const int bid = blockIdx.x;
  const int swz = (bid & 7) * 128 + (bid >> 3);
  const int brow = (swz >> 3) << 8;
  const int bcol = (swz & 7) << 8;
  const int cgrp = bcol >> 8;

  // staging coords: 2 threads per row
  const int s_r = t >> 1;           // 0..255
  const int s_h = t & 1;            // k-half within tile

  // A fragment read bases (chunk XOR folded)
  const int axor = lr & 7;
  const char* aBk[2];
  aBk[0] = (const char*)lds + (wm*128 + lr)*128 + (((0*4+lg)^axor) << 4);
  aBk[1] = (const char*)lds + (wm*128 + lr)*128 + (((1*4+lg)^axor) << 4);

  f32x4 acc[8][4] = {};
  bf16x8 aR[4][2];
  bf16x8 bH0[2][2], bH1[2][2];      // B half-tile banks (32 regs)

  // ---- prologue: reg-stage tiles 0 -> buf0, 1 -> buf1; B(0) -> banks
  {
    float4 fP[4];
    LOADH(fP, 0, 0); WRITEH(fP, 0, 0);
    LOADH(fP, 0, 1); WRITEH(fP, 0, 1);
    LOADH(fP, 1, 0); WRITEH(fP, 16384, 0);
    LOADH(fP, 1, 1); WRITEH(fP, 16384, 1);
  }
  GLBH(bH0, 0, 0); GLBH(bH1, 0, 1);
  LGKM0();
  BAR();

  // 17 segments; segment tt: compute tile tt (A in buf tt%3, B in bH0/bH1),
  // refill bH* with B(tt+1) after last use, reg-stage A tile tt+2 into buf (tt+2)%3.
  // Sync: ds-writes drained by LGKM0 before BAR; B/A global loads compiler-tracked (vmcnt).
  #pragma unroll
  for (int tt = 0; tt < 17; ++tt){
    const int cbuf = (tt % 3) * 32768;               // byte offset for LDA
    const int sbo  = ((tt + 2) % 3) * 16384;         // ushort offset for stage dest
    const int st   = (tt + 2 <= 16) ? tt + 2 : 16;   // clamp: duplicate restage, unread
    const int nk   = (tt + 1 <= 16) ? tt + 1 : 16;

    float4 fS0[4], fS1[4];
    LDA_T(cbuf, 0);
    if (st < 16) LOADH(fS0, st, 0);                  // issue A f32 batch 0 early
    MMA(0, 0, bH0);
    MMA(0, 1, bH1);
    LDA_T(cbuf, 1);
    if (st < 16) LOADH(fS1, st, 1);                  // batch 1 mid-segment
    MMA(1, 0, bH0);
    GLBH(bH0, nk, 0);                                // refill half 0 (last use was MMA(1,0))
    if (st < 16) WRITEH(fS0, sbo, 0);                // cvt+write under MFMA shadow
    MMA(1, 1, bH1);
    GLBH(bH1, nk, 1);                                // refill half 1
    if (st < 16) { WRITEH(fS1, sbo, 1); } else { STAGE_TAIL(sbo); }
    LGKM0();                                         // drain ds reads+writes before barrier
    BAR();
  }

  // ---- fused epilogue (all waves past final BAR -> loop LDS dead) ----
  // Batch 1 of W2 fragments (ks 0..3): issue now, latency hides under silu/ds_writes.
  bf16x8 w2fA[4][4];
  #pragma unroll
  for (int ks = 0; ks < 4; ++ks)
    #pragma unroll
    for (int ni = 0; ni < 4; ++ni)
      w2fA[ks][ni] = *(const bf16x8*)(w2t + (size_t)(ni*16 + lr) * HID + bcol + ks*32 + lg*8);

  float b1v[4];
  #pragma unroll
  for (int ni = 0; ni < 4; ++ni) b1v[ni] = b1[bcol + wn*64 + ni*16 + lr];

  // silu + pack to bf16; scatter into LDS as [row 256][col 256] with chunk-XOR swizzle
  #pragma unroll
  for (int mi = 0; mi < 8; ++mi){
    #pragma unroll
    for (int ni = 0; ni < 4; ++ni){
      const int col = wn*64 + ni*16 + lr;
      #pragma unroll
      for (int i2 = 0; i2 < 4; ++i2){
        const int row = wm*128 + mi*16 + lg*4 + i2;
        float v = acc[mi][ni][i2] + b1v[ni];
        float s = v / (1.0f + __expf(-v));     // silu
        const int chunk = (col >> 3) ^ (row & 7);
        lds[row*256 + chunk*8 + (col & 7)] = f2bf(s);
      }
    }
  }
  __syncthreads();

  // Batch 2 of W2 fragments (ks 4..7): latency hides under first 4 ks of MFMA.
  bf16x8 w2fB[4][4];
  #pragma unroll
  for (int ks = 0; ks < 4; ++ks)
    #pragma unroll
    for (int ni = 0; ni < 4; ++ni)
      w2fB[ks][ni] = *(const bf16x8*)(w2t + (size_t)(ni*16 + lr) * HID + bcol + (ks+4)*32 + lg*8);

  // mini-GEMM: partial[r][n] = hTile[r][:256] @ W2chunk[:256][n], n in [0,64)
  const int rb = wid * 32;
  f32x4 acc2[2][4] = {};
  #pragma unroll
  for (int ks = 0; ks < 8; ++ks){
    bf16x8 a2[2];
    #pragma unroll
    for (int m = 0; m < 2; ++m){
      const int row = rb + m*16 + lr;
      a2[m] = *(const bf16x8*)(lds + row*256 + (((ks*4+lg) ^ (lr & 7)) << 3));
    }
    #pragma unroll
    for (int m = 0; m < 2; ++m)
      #pragma unroll
      for (int ni = 0; ni < 4; ++ni)
        acc2[m][ni] = __builtin_amdgcn_mfma_f32_16x16x32_bf16(
            a2[m], (ks < 4) ? w2fA[ks & 3][ni] : w2fB[ks & 3][ni], acc2[m][ni], 0, 0, 0);
  }

  // store partials: pbuf[cb][row][col]
  const int cb = cgrp;
  #pragma unroll
  for (int m = 0; m < 2; ++m)
    #pragma unroll
    for (int ni = 0; ni < 4; ++ni)
      #pragma unroll
      for (int i2 = 0; i2 < 4; ++i2){
        const int r = brow + rb + m*16 + lg*4 + i2;
        pbuf[((size_t)cb << 21) + ((size_t)r << 6) + ni*16 + lr] = acc2[m][ni][i2];
      }
}

// ---------------- reduce: sum partials + b2 -> log-softmax -> NLL ----------------
__global__ __launch_bounds__(256) void k_red(const float* __restrict__ pbuf,
                                             const float* __restrict__ b2,
                                             const int* __restrict__ tgt,
                                             float* __restrict__ loss)
{
  const int lane = threadIdx.x & 63, w = threadIdx.x >> 6;
  const int row0 = blockIdx.x * 128 + w * 32;
  const float bias = (lane < 37) ? b2[lane] : 0.0f;
  for (int i = 0; i < 32; ++i){
    const int r = row0 + i;
    float s = 0.0f;
    #pragma unroll
    for (int cb = 0; cb < 8; ++cb)
      s += pbuf[((size_t)cb << 21) + ((size_t)r << 6) + lane];
    float x = (lane < 37) ? (s + bias) : -1e30f;
    float m = x;
    #pragma unroll
    for (int off = 1; off < 64; off <<= 1) m = fmaxf(m, __shfl_xor(m, off, 64));
    float e = __expf(x - m);
    float se = e;
    #pragma unroll
    for (int off = 1; off < 64; off <<= 1) se += __shfl_xor(se, off, 64);
    const int tg = tgt[r];
    const float pick = __shfl(x, tg, 64);
    if (lane == 0) loss[r] = m + __logf(se) - pick;
  }
}

// ---------------- launch ----------------
extern "C" void kernel_launch(void* const* d_in, const int* in_sizes, int n_in,
                              void* d_out, int out_size, void* d_ws, size_t ws_size,
                              hipStream_t stream)
{
  (void)in_sizes; (void)n_in; (void)out_size; (void)ws_size;
  const float* fc  = (const float*)d_in[0];
  const float* cam = (const float*)d_in[1];
  const float* ru  = (const float*)d_in[2];
  const float* W1  = (const float*)d_in[3];
  const float* b1  = (const float*)d_in[4];
  const float* W2  = (const float*)d_in[5];
  const float* b2  = (const float*)d_in[6];
  const int* afb = (const int*)d_in[7];
  const int* alr = (const int*)d_in[8];
  const int* ajp = (const int*)d_in[9];
  const int* ass = (const int*)d_in[10];
  const int* aat = (const int*)d_in[11];
  float* loss = (float*)d_out;

  // workspace layout (bytes):
  // xtail: 32768 x 64 bf16   =  4,194,304
  // w1p  : packed 2048x1088  =  4,456,448
  // w2t  : 64 x 2048 bf16    =    262,144
  // tgt  : 32768 int32       =    131,072
  // pbuf : 8 x 32768 x 64 f32= 67,108,864   (total ~76 MiB)
  char* ws = (char*)d_ws;
  unsigned short* xtail = (unsigned short*)(ws);
  unsigned short* w1p   = (unsigned short*)(ws + 4194304);
  unsigned short* w2t   = (unsigned short*)(ws + 8650752);
  int*            tgt   = (int*)           (ws + 8912896);
  float*          pbuf  = (float*)         (ws + 9043968);

  // prep: w1-pack(544) + w2t(512) + disc(128) = 1184 blocks
  k_prep<<<1184, 256, 0, stream>>>(W1, W2, cam, ru, afb, alr, ajp, ass, aat,
                                   xtail, w1p, w2t, tgt);
  k_gemm1<<<(B_ROWS/256) * (HID/256), 512, 0, stream>>>(fc, xtail, w1p, w2t, b1, pbuf);
  k_red  <<<B_ROWS / 128, 256, 0, stream>>>(pbuf, b2, tgt, loss);
}

// Round 12
// 267.374 us; speedup vs baseline: 1.1596x; 1.1596x over previous
//
#include <hip/hip_runtime.h>
#include <hip/hip_bf16.h>
#include <stdint.h>

// Problem constants
#define B_ROWS 32768
#define NUM_IN 1024
#define D_PAD2 1088   // 1064 padded to 17*64 K-tiles
#define HID    2048
#define NPAD   64     // 37 logits padded to 64

typedef __attribute__((ext_vector_type(8))) short bf16x8;
typedef __attribute__((ext_vector_type(4))) float f32x4;
typedef unsigned short ushort_t;

__device__ __forceinline__ unsigned short f2bf(float f){
  union { float f; uint32_t u; } x; x.f = f;
  uint32_t u = x.u;
  return (unsigned short)((u + 0x7FFFu + ((u >> 16) & 1u)) >> 16);
}

__device__ __forceinline__ float bf2f(unsigned short u){
  union { uint32_t u; float f; } x; x.u = ((uint32_t)u) << 16;
  return x.f;
}

__device__ __forceinline__ void gload16(const void* g, void* l){
  __builtin_amdgcn_global_load_lds((const __attribute__((address_space(1))) void*)g,
                                   (__attribute__((address_space(3))) void*)l, 16, 0, 0);
}

// ---------------- discretizer scan (per batch element) ----------------
__device__ __forceinline__ int disc_step(
    float cam0, float cam1, const int a[5],
    float& ac0, float& ac1, float& delta,
    int r[5], bool& dch, int& cam_steps, bool& committed, float& norm)
{
  const int RS[5] = {6, 8, 10, 11, 14};
  norm += committed ? 0.0f : 1.0f;
  bool commit = ((fabsf(cam0) < 1e-5f) && (fabsf(cam1) < 1e-5f)) || (cam_steps >= 6);
  #pragma unroll
  for (int i = 0; i < 5; ++i) commit = commit && (r[i] == a[i]);
  int dac = 0;
  bool modified = commit;
  #pragma unroll
  for (int i = 0; i < 5; ++i){
    bool disc = (!modified) && (r[i] != a[i]);
    if (disc){
      dac = (a[i] == 0) ? (r[i] - 1 + RS[i]) : (a[i] - 1 + RS[i]);
      r[i] = a[i];
      modified = true;
    }
  }
  float d2 = delta * 2.0f;
  // NOTE: reference compares BOTH cam0 and cam1 against ac[:,0] — replicate.
  bool dmask = (!modified) && (!dch) &&
               ((fabsf(cam0 - ac0) > d2) || (fabsf(cam1 - ac0) > d2));
  if (dmask){ dac = 5; delta = fminf(d2, 0.5f); modified = true; }
  if (!modified){
    float sx = (cam0 < ac0) ? -1.0f : 1.0f;
    float sy = (cam1 < ac1) ? -1.0f : 1.0f;
    dac = (sx < 0.0f) ? ((sy < 0.0f) ? 1 : 3) : ((sy < 0.0f) ? 2 : 4);
    ac0 += sx * delta; ac1 += sy * delta;
    delta *= 0.5f;
    dch = true;
    cam_steps += 1;
  }
  committed = committed || commit;
  return dac;
}

// ---------------- fused prep: fc convert | W1^T (LDS transpose) | W2^T | disc ----------------
// block ranges: [0,16384) fc ; [16384,16928) w1t-transpose ; [16928,17440) w2t ; [17440,17568) disc
__global__ void k_prep(const float* __restrict__ fc, const float* __restrict__ W1,
                       const float* __restrict__ W2,
                       const float* __restrict__ camera, const float* __restrict__ rand_u,
                       const int* __restrict__ afb, const int* __restrict__ alr,
                       const int* __restrict__ ajp, const int* __restrict__ ass,
                       const int* __restrict__ aat,
                       unsigned short* __restrict__ xb, unsigned short* __restrict__ w1t,
                       unsigned short* __restrict__ w2t, int* __restrict__ tgt)
{
  __shared__ float lt[64][65];      // transpose tile (+1 pad, conflict-free)
  const int b = blockIdx.x;
  const int tid = threadIdx.x;
  if (b < 16384){
    int gid = b * 256 + tid;
    int row = gid >> 7;
    int c   = gid & 127;
    const float4* p = (const float4*)(fc + (size_t)row * NUM_IN + c * 8);
    float4 f0 = p[0], f1 = p[1];
    uint4 pk;
    pk.x = (uint32_t)f2bf(f0.x) | ((uint32_t)f2bf(f0.y) << 16);
    pk.y = (uint32_t)f2bf(f0.z) | ((uint32_t)f2bf(f0.w) << 16);
    pk.z = (uint32_t)f2bf(f1.x) | ((uint32_t)f2bf(f1.y) << 16);
    pk.w = (uint32_t)f2bf(f1.z) | ((uint32_t)f2bf(f1.w) << 16);
    *(uint4*)(xb + (size_t)row * D_PAD2 + c * 8) = pk;
    return;
  }
  if (b < 16928){
    // W1 [1064][2048] -> w1t [2048][1088] via 64x64 LDS tile; coalesced both sides
    const int bi = b - 16384;
    const int kt = bi % 17, nt = bi / 17;
    const int k0 = kt * 64, n0 = nt * 64;
    const int c = tid & 63, rq = tid >> 6;
    #pragma unroll
    for (int rr = 0; rr < 16; ++rr){
      const int r = rr * 4 + rq;
      const int k = k0 + r;
      lt[r][c] = (k < 1064) ? W1[(size_t)k * HID + n0 + c] : 0.0f;
    }
    __syncthreads();
    #pragma unroll
    for (int rr = 0; rr < 16; ++rr){
      const int r = rr * 4 + rq;
      w1t[(size_t)(n0 + r) * D_PAD2 + k0 + c] = f2bf(lt[c][r]);
    }
    return;
  }
  if (b < 17440){
    int idx = (b - 16928) * 256 + tid;
    int n = idx >> 11;
    int k = idx & (HID - 1);
    float v = (n < 37) ? W2[(size_t)k * 37 + n] : 0.0f;
    w2t[idx] = f2bf(v);
    return;
  }
  // discretizer
  int row = (b - 17440) * 256 + tid;
  float cam0 = camera[2*row], cam1 = camera[2*row + 1];
  int a[5] = { afb[row], alr[row], ajp[row], ass[row], aat[row] };

  float ac0 = 0.f, ac1 = 0.f, delta = 0.0625f, norm = 0.f;
  int r[5] = {0,0,0,0,0};
  bool dch = false, committed = false; int cam_steps = 0;
  for (int t = 0; t < 20; ++t)
    disc_step(cam0, cam1, a, ac0, ac1, delta, r, dch, cam_steps, committed, norm);

  int rs = (int)(rand_u[row] * norm);
  if (rs > 19) rs = 19;
  if (rs < 0) rs = 0;

  ac0 = 0.f; ac1 = 0.f; delta = 0.0625f; norm = 0.f;
  r[0]=r[1]=r[2]=r[3]=r[4]=0; dch = false; committed = false; cam_steps = 0;
  for (int t = 0; t < rs; ++t)
    disc_step(cam0, cam1, a, ac0, ac1, delta, r, dch, cam_steps, committed, norm);

  float vec[40];
  #pragma unroll
  for (int j = 0; j < 40; ++j) vec[j] = 0.0f;
  vec[0] = ac0; vec[1] = ac1;
  const int offs[5] = {2, 5, 8, 10, 14};
  #pragma unroll
  for (int i = 0; i < 5; ++i) vec[offs[i] + r[i]] = 1.0f;
  vec[38] = delta; vec[39] = dch ? 1.0f : 0.0f;

  int dac = disc_step(cam0, cam1, a, ac0, ac1, delta, r, dch, cam_steps, committed, norm);
  tgt[row] = dac;

  unsigned short* o = xb + (size_t)row * D_PAD2 + NUM_IN;
  #pragma unroll
  for (int j = 0; j < 40; ++j) o[j] = f2bf(vec[j]);
  #pragma unroll
  for (int j = 40; j < 64; ++j) o[j] = 0;
}

// ---------------- GEMM1: 128x128 m97-structure, 4 waves, 3 blocks/CU + fused W2 ----------------
// LDS 32 KB: A [128][64] at ushort 0, B [128][64] at ushort 8192. Epilogue: h [128][128].

#define BAR() __syncthreads()

__global__ __launch_bounds__(256, 3) void k_gemm1(const ushort_t* __restrict__ xb,
                                                  const ushort_t* __restrict__ w1t,
                                                  const ushort_t* __restrict__ w2t,
                                                  const float* __restrict__ b1,
                                                  ushort_t* __restrict__ pbuf)
{
  __shared__ ushort_t lds[16384];   // 32 KiB
  const int t = threadIdx.x;        // 0..255
  const int lane = t & 63;
  const int wid = t >> 6;           // 4 waves: 2x2, wave tile 64x64
  const int wm = wid >> 1, wn = wid & 1;
  const int lr = lane & 15, lg = lane >> 4;

  // XCD-aware swizzle (nwg=4096, %8==0 -> bijective). 512 blocks/XCD chunk:
  // 32 row-tiles x 16 col-tiles -> A panel reused 16x within an XCD's L2.
  const int bid = blockIdx.x;
  const int swz = (bid & 7) * 512 + (bid >> 3);
  const int brow = (swz >> 4) << 7;   // 256 row tiles of 128
  const int bcol = (swz & 15) << 7;   // 16 col tiles of 128
  const int cb   = swz & 15;

  // fragment read bases (chunk XOR folded; rows are 64 ushort = 128 B)
  const int axor = lr & 7;
  const char* aBk[2];
  const char* bBk[2];
  aBk[0] = (const char*)lds + (wm*64 + lr)*128 + (((0 + lg) ^ axor) << 4);
  aBk[1] = (const char*)lds + (wm*64 + lr)*128 + (((4 + lg) ^ axor) << 4);
  bBk[0] = (const char*)lds + 16384 + (wn*64 + lr)*128 + (((0 + lg) ^ axor) << 4);
  bBk[1] = (const char*)lds + 16384 + (wn*64 + lr)*128 + (((4 + lg) ^ axor) << 4);

  f32x4 acc[4][4] = {};
  bf16x8 aR[4][2], bR[4][2];

  for (int kt = 0; kt < 17; ++kt){
    // stage A and B tiles into the single buffer (linear dest, pre-swizzled source)
    #pragma unroll
    for (int s = 0; s < 4; ++s){
      const int sr = s*32 + (t >> 3);
      const int sc = ((t & 7) ^ (sr & 7)) << 3;
      gload16(xb  + (size_t)(brow + sr) * D_PAD2 + (kt << 6) + sc, lds + s*2048 + t*8);
      gload16(w1t + (size_t)(bcol + sr) * D_PAD2 + (kt << 6) + sc, lds + 8192 + s*2048 + t*8);
    }
    BAR();   // compiler drains vmcnt(0) before s_barrier

    #pragma unroll
    for (int mi = 0; mi < 4; ++mi)
      #pragma unroll
      for (int kk = 0; kk < 2; ++kk)
        aR[mi][kk] = *(const bf16x8*)(aBk[kk] + mi*16*128);
    #pragma unroll
    for (int ni = 0; ni < 4; ++ni)
      #pragma unroll
      for (int kk = 0; kk < 2; ++kk)
        bR[ni][kk] = *(const bf16x8*)(bBk[kk] + ni*16*128);

    __builtin_amdgcn_s_setprio(1);
    #pragma unroll
    for (int mi = 0; mi < 4; ++mi)
      #pragma unroll
      for (int ni = 0; ni < 4; ++ni)
        #pragma unroll
        for (int kk = 0; kk < 2; ++kk)
          acc[mi][ni] = __builtin_amdgcn_mfma_f32_16x16x32_bf16(
              aR[mi][kk], bR[ni][kk], acc[mi][ni], 0, 0, 0);
    __builtin_amdgcn_s_setprio(0);
    BAR();   // protect LDS from next iteration's staging
  }

  // ---- fused epilogue: silu -> LDS h-tile [128][128] -> mini-GEMM vs W2 chunk ----
  float b1v[4];
  #pragma unroll
  for (int ni = 0; ni < 4; ++ni) b1v[ni] = b1[bcol + wn*64 + ni*16 + lr];

  #pragma unroll
  for (int mi = 0; mi < 4; ++mi){
    #pragma unroll
    for (int ni = 0; ni < 4; ++ni){
      const int col = wn*64 + ni*16 + lr;
      #pragma unroll
      for (int i2 = 0; i2 < 4; ++i2){
        const int row = wm*64 + mi*16 + lg*4 + i2;
        float v = acc[mi][ni][i2] + b1v[ni];
        float s = v / (1.0f + __expf(-v));     // silu
        const int c = col >> 3;                 // 0..15
        lds[row*128 + ((c ^ (row & 7)) << 3) + (col & 7)] = f2bf(s);
      }
    }
  }
  BAR();

  // W2 fragments for this block's 128 k-cols (K=128 -> 4 ks steps)
  bf16x8 w2f[4][4];
  #pragma unroll
  for (int ks = 0; ks < 4; ++ks)
    #pragma unroll
    for (int ni = 0; ni < 4; ++ni)
      w2f[ks][ni] = *(const bf16x8*)(w2t + (size_t)(ni*16 + lr) * HID + bcol + ks*32 + lg*8);

  // mini-GEMM: partial[r][n] = hTile[r][:128] @ W2chunk[:128][n], n in [0,64)
  const int rb = wid * 32;
  f32x4 acc2[2][4] = {};
  #pragma unroll
  for (int ks = 0; ks < 4; ++ks){
    bf16x8 a2[2];
    #pragma unroll
    for (int m = 0; m < 2; ++m){
      const int row = rb + m*16 + lr;
      const int c = ks*4 + lg;
      a2[m] = *(const bf16x8*)(lds + row*128 + ((c ^ (row & 7)) << 3));
    }
    #pragma unroll
    for (int m = 0; m < 2; ++m)
      #pragma unroll
      for (int ni = 0; ni < 4; ++ni)
        acc2[m][ni] = __builtin_amdgcn_mfma_f32_16x16x32_bf16(
            a2[m], w2f[ks][ni], acc2[m][ni], 0, 0, 0);
  }

  // store bf16 partials: pbuf[cb][row][col]  (rows contiguous 128 B)
  #pragma unroll
  for (int m = 0; m < 2; ++m)
    #pragma unroll
    for (int ni = 0; ni < 4; ++ni)
      #pragma unroll
      for (int i2 = 0; i2 < 4; ++i2){
        const int r = brow + rb + m*16 + lg*4 + i2;
        pbuf[((size_t)cb << 21) + ((size_t)r << 6) + ni*16 + lr] = f2bf(acc2[m][ni][i2]);
      }
}

// ---------------- reduce: sum 16 bf16 partials + b2 -> log-softmax -> NLL ----------------
__global__ __launch_bounds__(256) void k_red(const ushort_t* __restrict__ pbuf,
                                             const float* __restrict__ b2,
                                             const int* __restrict__ tgt,
                                             float* __restrict__ loss)
{
  const int lane = threadIdx.x & 63, w = threadIdx.x >> 6;
  const int row0 = blockIdx.x * 128 + w * 32;
  const float bias = (lane < 37) ? b2[lane] : 0.0f;
  for (int i = 0; i < 32; ++i){
    const int r = row0 + i;
    float s = 0.0f;
    #pragma unroll
    for (int cbk = 0; cbk < 16; ++cbk)
      s += bf2f(pbuf[((size_t)cbk << 21) + ((size_t)r << 6) + lane]);
    float x = (lane < 37) ? (s + bias) : -1e30f;
    float m = x;
    #pragma unroll
    for (int off = 1; off < 64; off <<= 1) m = fmaxf(m, __shfl_xor(m, off, 64));
    float e = __expf(x - m);
    float se = e;
    #pragma unroll
    for (int off = 1; off < 64; off <<= 1) se += __shfl_xor(se, off, 64);
    const int tg = tgt[r];
    const float pick = __shfl(x, tg, 64);
    if (lane == 0) loss[r] = m + __logf(se) - pick;
  }
}

// ---------------- launch ----------------
extern "C" void kernel_launch(void* const* d_in, const int* in_sizes, int n_in,
                              void* d_out, int out_size, void* d_ws, size_t ws_size,
                              hipStream_t stream)
{
  (void)in_sizes; (void)n_in; (void)out_size; (void)ws_size;
  const float* fc  = (const float*)d_in[0];
  const float* cam = (const float*)d_in[1];
  const float* ru  = (const float*)d_in[2];
  const float* W1  = (const float*)d_in[3];
  const float* b1  = (const float*)d_in[4];
  const float* W2  = (const float*)d_in[5];
  const float* b2  = (const float*)d_in[6];
  const int* afb = (const int*)d_in[7];
  const int* alr = (const int*)d_in[8];
  const int* ajp = (const int*)d_in[9];
  const int* ass = (const int*)d_in[10];
  const int* aat = (const int*)d_in[11];
  float* loss = (float*)d_out;

  // workspace layout (bytes):
  // xb   : 32768 x 1088 bf16   = 71,303,168
  // w1t  : 2048 x 1088 bf16    =  4,456,448
  // w2t  : 64 x 2048 bf16      =    262,144
  // tgt  : 32768 int32         =    131,072
  // pbuf : 16 x 32768 x 64 bf16= 67,108,864   (total ~136.6 MiB)
  char* ws = (char*)d_ws;
  unsigned short* xb  = (unsigned short*)(ws);
  unsigned short* w1t = (unsigned short*)(ws + 71303168);
  unsigned short* w2t = (unsigned short*)(ws + 75759616);
  int*            tgt = (int*)           (ws + 76021760);
  unsigned short* pbuf= (unsigned short*)(ws + 76152832);

  // fused prep: fc(16384) + w1t-transpose(544) + w2t(512) + disc(128) = 17568 blocks
  k_prep<<<17568, 256, 0, stream>>>(fc, W1, W2, cam, ru, afb, alr, ajp, ass, aat,
                                    xb, w1t, w2t, tgt);
  k_gemm1<<<(B_ROWS/128) * (HID/128), 256, 0, stream>>>(xb, w1t, w2t, b1, pbuf);
  k_red  <<<B_ROWS / 128, 256, 0, stream>>>(pbuf, b2, tgt, loss);
}